// Round 6
// baseline (315.577 us; speedup 1.0000x reference)
//
#include <hip/hip_runtime.h>
#include <hip/hip_bf16.h>
#include <stdint.h>

#define HEADS 16
#define HD 64
#define SEQ 2048
#define BATCH 2
#define CDIM 1024
#define MROWS (BATCH*SEQ)   // 4096
#define K3C (3*CDIM)        // 3072
// Q prescale: attn scale 1/8 times log2(e), so softmax uses exp2 directly
#define QSCALE 0.1803368801111244f

typedef __bf16 bf16x8 __attribute__((ext_vector_type(8)));
typedef float  f32x4  __attribute__((ext_vector_type(4)));

__device__ __forceinline__ unsigned short f2bf(float f) {
    __hip_bfloat16 h = __float2bfloat16(f);
    return __builtin_bit_cast(unsigned short, h);
}
__device__ __forceinline__ unsigned int pack2bf(float a, float b) {
    return (unsigned int)f2bf(a) | ((unsigned int)f2bf(b) << 16);
}
__device__ __forceinline__ bf16x8 frag(uint4 u) { return __builtin_bit_cast(bf16x8, u); }

// async global->LDS: per-lane global gather -> contiguous LDS (base + lane*16)
__device__ __forceinline__ void async16(const unsigned short* g, unsigned short* lds) {
    __builtin_amdgcn_global_load_lds(
        (const __attribute__((address_space(1))) unsigned int*)g,
        (__attribute__((address_space(3))) unsigned int*)lds, 16, 0, 0);
}

// ---------------- fused cast + W-shuffle kernel ----------------
// blocks [0,4096): pack one row of q|k|v -> A bf16 [4096][3072]
// blocks [4096,8704): shuffle-cast W_qkv (3072x3072): 192 n-tiles x 24 k-groups
// blocks [8704,9216): shuffle-cast W_proj (1024x1024): 64 n-tiles x 8 k-groups
// Shuffled layout: cell (nt,kc) holds 512 elems; elem (l15,quad,j) at
// l15*32+quad*8+j  =  W[nt*16+l15][kc*32+quad*8+j]  (exact MFMA B-frag order).
__device__ __forceinline__ void shuf_cell(const float* __restrict__ W, unsigned short* __restrict__ Ws,
                                          int N, int K, int bid, int t)
{
    const int KG = K >> 7;              // k-groups of 128
    const int nt = bid / KG;
    const int kc = (bid % KG)*4 + (t >> 6);
    const int idx = t & 63;
    const int l15 = idx & 15;
    const int quad = idx >> 4;
    const float* src = W + (size_t)(nt*16 + l15)*K + kc*32 + quad*8;
    float4 f0 = *(const float4*)(src);
    float4 f1 = *(const float4*)(src + 4);
    uint4 d;
    d.x = pack2bf(f0.x, f0.y); d.y = pack2bf(f0.z, f0.w);
    d.z = pack2bf(f1.x, f1.y); d.w = pack2bf(f1.z, f1.w);
    *(uint4*)(Ws + ((size_t)nt*(K>>5) + kc)*512 + l15*32 + quad*8) = d;
}

__global__ void cast_all(const float* __restrict__ q, const float* __restrict__ k,
                         const float* __restrict__ v, const float* __restrict__ Wq,
                         const float* __restrict__ Wp,
                         unsigned short* __restrict__ A, unsigned short* __restrict__ Wqb,
                         unsigned short* __restrict__ Wpb)
{
    const int bid = blockIdx.x;
    const int t = threadIdx.x;
    if (bid < MROWS) {
        const float* srcs[3] = {q, k, v};
        #pragma unroll
        for (int i = 0; i < 3; ++i) {
            float4 f = *(const float4*)(srcs[i] + (size_t)bid*CDIM + t*4);
            ushort4 s;
            s.x = f2bf(f.x); s.y = f2bf(f.y); s.z = f2bf(f.z); s.w = f2bf(f.w);
            *(ushort4*)(A + (size_t)bid*K3C + i*CDIM + t*4) = s;
        }
    } else if (bid < MROWS + 4608) {
        shuf_cell(Wq, Wqb, K3C, K3C, bid - MROWS, t);
    } else {
        shuf_cell(Wp, Wpb, CDIM, CDIM, bid - MROWS - 4608, t);
    }
}

// ---------------- flatmm-style bf16 GEMM ----------------
// A staged in LDS (double-buffered, async); B pre-shuffled, streamed straight to
// VGPRs via coalesced global_load_dwordx4. Per iter: issue B(kt+1)+A(kt+1),
// s_waitcnt vmcnt(6) (kt landed, kt+1 in flight), raw s_barrier. 2 barriers/iter.
template<int EPI>
__global__ __launch_bounds__(256, 2)
void gemm_flat(const unsigned short* __restrict__ A, const unsigned short* __restrict__ Bsh,
               int M, int N, int K,
               unsigned short* __restrict__ qh, unsigned short* __restrict__ kh,
               unsigned short* __restrict__ vt,
               const float* __restrict__ bias, float* __restrict__ out)
{
    __shared__ __attribute__((aligned(16))) unsigned short As[2][128*32];
    const int tid  = threadIdx.x;
    const int wave = tid >> 6;
    const int lane = tid & 63;
    const int l15  = lane & 15;
    const int quad = lane >> 4;
    const int wm = (wave >> 1) * 64;
    const int wn = (wave & 1) * 64;
    const int m0 = blockIdx.x * 128;
    const int n0 = blockIdx.y * 128;
    const int KC = K >> 5;

    f32x4 acc[4][4] = {};

    const int srow = tid >> 2;          // A staging: row within 64-row half
    const int sc8  = (tid & 3) * 8;

    auto stageA = [&](int kc, int bufI) {
        #pragma unroll
        for (int t = 0; t < 2; ++t) {
            int row = t*64 + srow;
            async16(A + (size_t)(m0 + row)*K + kc*32 + sc8,
                    &As[bufI][(t*256 + wave*64)*8]);
        }
    };

    // B fragment base: frag i covers n-tile (n0+wn)/16 + i
    const unsigned short* bbase = Bsh + ((size_t)((n0 + wn) >> 4) * KC) * 512 + l15*32 + quad*8;

    uint4 bcur[4], bnxt[4];
    #pragma unroll
    for (int i = 0; i < 4; ++i)
        bcur[i] = *(const uint4*)(bbase + (size_t)i*KC*512);
    stageA(0, 0);

    #pragma unroll 2
    for (int kc = 0; kc < KC; ++kc) {
        int kn = kc + 1;
        if (kn < KC) {
            #pragma unroll
            for (int i = 0; i < 4; ++i)
                bnxt[i] = *(const uint4*)(bbase + (size_t)i*KC*512 + (size_t)kn*512);
            stageA(kn, kn & 1);
            asm volatile("s_waitcnt vmcnt(6)" ::: "memory");
        } else {
            asm volatile("s_waitcnt vmcnt(0)" ::: "memory");
        }
        asm volatile("s_barrier" ::: "memory");

        const unsigned short* Ab = As[kc & 1];
        uint4 af[4];
        #pragma unroll
        for (int i = 0; i < 4; ++i)
            af[i] = *(const uint4*)&Ab[(wm + i*16 + l15)*32 + quad*8];

        #pragma unroll
        for (int mi = 0; mi < 4; ++mi)
            #pragma unroll
            for (int ni = 0; ni < 4; ++ni)
                acc[mi][ni] = __builtin_amdgcn_mfma_f32_16x16x32_bf16(
                    frag(af[mi]), frag(bcur[ni]), acc[mi][ni], 0, 0, 0);

        #pragma unroll
        for (int i = 0; i < 4; ++i) bcur[i] = bnxt[i];

        asm volatile("s_barrier" ::: "memory");
    }

    if constexpr (EPI == 0) {
        #pragma unroll
        for (int mi = 0; mi < 4; ++mi) {
            int row0 = m0 + wm + mi*16 + quad*4;
            int b  = row0 >> 11;
            int nq = row0 & 2047;
            #pragma unroll
            for (int ni = 0; ni < 4; ++ni) {
                int col   = n0 + wn + ni*16 + l15;
                int which = col >> 10;
                int h     = (col >> 6) & 15;
                int d     = col & 63;
                int bh    = b*HEADS + h;
                if (which == 2) {
                    ushort4 pv;
                    pv.x = f2bf(acc[mi][ni][0]);
                    pv.y = f2bf(acc[mi][ni][1]);
                    pv.z = f2bf(acc[mi][ni][2]);
                    pv.w = f2bf(acc[mi][ni][3]);
                    *(ushort4*)&vt[((size_t)bh*HD + d)*SEQ + nq] = pv;
                } else {
                    unsigned short* dst = (which == 0) ? qh : kh;
                    float sc = (which == 0) ? QSCALE : 1.0f;
                    #pragma unroll
                    for (int r = 0; r < 4; ++r)
                        dst[((size_t)bh*SEQ + nq + r)*HD + d] = f2bf(acc[mi][ni][r] * sc);
                }
            }
        }
    } else {
        #pragma unroll
        for (int mi = 0; mi < 4; ++mi) {
            int row0 = m0 + wm + mi*16 + quad*4;
            #pragma unroll
            for (int ni = 0; ni < 4; ++ni) {
                int col  = n0 + wn + ni*16 + l15;
                float bv = bias[col];
                #pragma unroll
                for (int r = 0; r < 4; ++r)
                    out[(size_t)(row0 + r)*N + col] = acc[mi][ni][r] + bv;
            }
        }
    }
}

// ---------------- flash attention: 32 q/wave + async double-buffered K/V ----------------
__global__ __launch_bounds__(256, 2)
void attention(const unsigned short* __restrict__ qh, const unsigned short* __restrict__ kh,
               const unsigned short* __restrict__ vt, unsigned short* __restrict__ xb)
{
    const int qt = blockIdx.x;          // 0..15 (tiles of 128 q)
    const int h  = blockIdx.y;
    const int b  = blockIdx.z;
    const int bh = b*HEADS + h;
    const int tid  = threadIdx.x;
    const int wave = tid >> 6;
    const int lane = tid & 63;
    const int l15  = lane & 15;
    const int quad = lane >> 4;

    __shared__ __attribute__((aligned(16))) unsigned short Ks[2][64*64];
    __shared__ __attribute__((aligned(16))) unsigned short Vs[2][64*64];
    __shared__ __attribute__((aligned(16))) unsigned short Ps[4][2*16*72];

    const unsigned short* Qp = qh + ((size_t)bh*SEQ + qt*128 + wave*32)*HD;
    const unsigned short* Kp = kh + (size_t)bh*SEQ*HD;
    const unsigned short* Vp = vt + (size_t)bh*HD*SEQ;

    auto stage = [&](int kt, int bufI) {
        #pragma unroll
        for (int t = 0; t < 2; ++t) {
            int c  = t*256 + wave*64 + lane;   // chunk index 0..511
            int r  = c >> 3;
            int cc = (c & 7) ^ (r & 7);
            async16(Kp + (size_t)(kt*64 + r)*HD + cc*8,
                    &Ks[bufI][(t*256 + wave*64)*8]);
            async16(Vp + (size_t)r*SEQ + kt*64 + cc*8,
                    &Vs[bufI][(t*256 + wave*64)*8]);
        }
    };

    stage(0, 0);

    uint4 qf[2][2];
    #pragma unroll
    for (int g = 0; g < 2; ++g) {
        qf[g][0] = *(const uint4*)(Qp + (size_t)(g*16 + l15)*HD + quad*8);
        qf[g][1] = *(const uint4*)(Qp + (size_t)(g*16 + l15)*HD + 32 + quad*8);
    }

    f32x4 o[2][4] = {};
    float m_s[2] = {-INFINITY, -INFINITY};
    float l_s[2] = {0.f, 0.f};

    unsigned short* Pw = Ps[wave];
    const int x7 = l15 & 7;

    for (int kt = 0; kt < SEQ/64; ++kt) {
        stage((kt + 1) & 31, (kt + 1) & 1);
        asm volatile("s_waitcnt vmcnt(4)" ::: "memory");
        asm volatile("s_barrier" ::: "memory");

        const unsigned short* Kb = Ks[kt & 1];
        const unsigned short* Vb = Vs[kt & 1];

        f32x4 s[2][4];
        #pragma unroll
        for (int st = 0; st < 4; ++st) {
            int rb = st*16 + l15;
            uint4 kf0 = *(const uint4*)&Kb[(rb*8 + (quad ^ x7))*8];
            uint4 kf1 = *(const uint4*)&Kb[(rb*8 + ((4 + quad) ^ x7))*8];
            #pragma unroll
            for (int g = 0; g < 2; ++g) {
                f32x4 z = {};
                z = __builtin_amdgcn_mfma_f32_16x16x32_bf16(frag(kf0), frag(qf[g][0]), z, 0, 0, 0);
                z = __builtin_amdgcn_mfma_f32_16x16x32_bf16(frag(kf1), frag(qf[g][1]), z, 0, 0, 0);
                s[g][st] = z;
            }
        }

        #pragma unroll
        for (int g = 0; g < 2; ++g) {
            float mloc = s[g][0][0];
            #pragma unroll
            for (int st = 0; st < 4; ++st)
                #pragma unroll
                for (int r = 0; r < 4; ++r)
                    mloc = fmaxf(mloc, s[g][st][r]);
            mloc = fmaxf(mloc, __shfl_xor(mloc, 16));
            mloc = fmaxf(mloc, __shfl_xor(mloc, 32));

            float mn = fmaxf(m_s[g], mloc);
            float al = __builtin_amdgcn_exp2f(m_s[g] - mn);
            m_s[g] = mn;

            float rs = 0.f;
            float p[4][4];
            #pragma unroll
            for (int st = 0; st < 4; ++st)
                #pragma unroll
                for (int r = 0; r < 4; ++r) {
                    p[st][r] = __builtin_amdgcn_exp2f(s[g][st][r] - mn);
                    rs += p[st][r];
                }
            rs += __shfl_xor(rs, 16);
            rs += __shfl_xor(rs, 32);
            l_s[g] = al*l_s[g] + rs;

            #pragma unroll
            for (int st = 0; st < 4; ++st)
                #pragma unroll
                for (int r = 0; r < 4; ++r)
                    o[g][st][r] *= al;

            #pragma unroll
            for (int st = 0; st < 4; ++st) {
                uint2 pk;
                pk.x = pack2bf(p[st][0], p[st][1]);
                pk.y = pack2bf(p[st][2], p[st][3]);
                *(uint2*)&Pw[g*1152 + l15*72 + st*16 + quad*4] = pk;
            }
        }
        asm volatile("s_waitcnt lgkmcnt(0)" ::: "memory");

        uint4 pB[2][2];
        #pragma unroll
        for (int g = 0; g < 2; ++g) {
            pB[g][0] = *(const uint4*)&Pw[g*1152 + l15*72 + quad*8];
            pB[g][1] = *(const uint4*)&Pw[g*1152 + l15*72 + 32 + quad*8];
        }

        #pragma unroll
        for (int st = 0; st < 4; ++st) {
            int rb = st*16 + l15;
            uint4 vf0 = *(const uint4*)&Vb[(rb*8 + (quad ^ x7))*8];
            uint4 vf1 = *(const uint4*)&Vb[(rb*8 + ((4 + quad) ^ x7))*8];
            #pragma unroll
            for (int g = 0; g < 2; ++g) {
                o[g][st] = __builtin_amdgcn_mfma_f32_16x16x32_bf16(frag(vf0), frag(pB[g][0]), o[g][st], 0, 0, 0);
                o[g][st] = __builtin_amdgcn_mfma_f32_16x16x32_bf16(frag(vf1), frag(pB[g][1]), o[g][st], 0, 0, 0);
            }
        }

        asm volatile("s_barrier" ::: "memory");
    }

    #pragma unroll
    for (int g = 0; g < 2; ++g) {
        float inv = 1.0f / l_s[g];
        #pragma unroll
        for (int st = 0; st < 4; ++st) {
            uint2 pk;
            pk.x = pack2bf(o[g][st][0]*inv, o[g][st][1]*inv);
            pk.y = pack2bf(o[g][st][2]*inv, o[g][st][3]*inv);
            *(uint2*)&Pw[g*1152 + l15*72 + st*16 + quad*4] = pk;
        }
    }
    asm volatile("s_waitcnt lgkmcnt(0)" ::: "memory");

    const int qr = lane >> 2;
    const int dd = (lane & 3) * 16;
    #pragma unroll
    for (int g = 0; g < 2; ++g) {
        uint4 oa = *(const uint4*)&Pw[g*1152 + qr*72 + dd];
        uint4 ob = *(const uint4*)&Pw[g*1152 + qr*72 + dd + 8];
        const int mrow = b*SEQ + qt*128 + wave*32 + g*16 + qr;
        *(uint4*)&xb[(size_t)mrow*CDIM + h*HD + dd]     = oa;
        *(uint4*)&xb[(size_t)mrow*CDIM + h*HD + dd + 8] = ob;
    }
}

extern "C" void kernel_launch(void* const* d_in, const int* in_sizes, int n_in,
                              void* d_out, int out_size, void* d_ws, size_t ws_size,
                              hipStream_t stream)
{
    const float* q  = (const float*)d_in[0];
    const float* k  = (const float*)d_in[1];
    const float* v  = (const float*)d_in[2];
    const float* Wq = (const float*)d_in[3];
    const float* Wp = (const float*)d_in[4];
    const float* bp = (const float*)d_in[5];
    float* out = (float*)d_out;

    char* p = (char*)d_ws;
    auto carve = [&](size_t bytes) { char* r = p; p += (bytes + 255) & ~(size_t)255; return r; };
    unsigned short* Abuf   = (unsigned short*)carve((size_t)MROWS*K3C*2);
    unsigned short* Wqkvb  = (unsigned short*)carve((size_t)K3C*K3C*2);
    unsigned short* Wprojb = (unsigned short*)carve((size_t)CDIM*CDIM*2);
    unsigned short* qhb    = (unsigned short*)carve((size_t)BATCH*HEADS*SEQ*HD*2);
    unsigned short* khb    = (unsigned short*)carve((size_t)BATCH*HEADS*SEQ*HD*2);
    unsigned short* vtb    = (unsigned short*)carve((size_t)BATCH*HEADS*SEQ*HD*2);
    unsigned short* xbuf   = (unsigned short*)carve((size_t)MROWS*CDIM*2);

    cast_all<<<MROWS + 4608 + 512, 256, 0, stream>>>(q, k, v, Wq, Wp, Abuf, Wqkvb, Wprojb);

    gemm_flat<0><<<dim3(MROWS/128, K3C/128), 256, 0, stream>>>(
        Abuf, Wqkvb, MROWS, K3C, K3C, qhb, khb, vtb, nullptr, nullptr);

    attention<<<dim3(SEQ/128, HEADS, BATCH), 256, 0, stream>>>(qhb, khb, vtb, xbuf);

    gemm_flat<1><<<dim3(MROWS/128, CDIM/128), 256, 0, stream>>>(
        xbuf, Wprojb, MROWS, CDIM, CDIM, nullptr, nullptr, nullptr, bp, out);
}